// Round 6
// baseline (238.255 us; speedup 1.0000x reference)
//
#include <hip/hip_runtime.h>

typedef unsigned short u16;
typedef short bf16x8 __attribute__((ext_vector_type(8)));
typedef short short4v __attribute__((ext_vector_type(4)));
typedef float floatx4 __attribute__((ext_vector_type(4)));

#define OUT_CTX 16777216           // 2*128*65536 attention elems
#define OUT_CLS (OUT_CTX + 512)
#define NBLK 512

__device__ __forceinline__ u16 f2b(float f) {           // fp32 -> bf16 RNE
  unsigned int u = __float_as_uint(f);
  u += 0x7fffu + ((u >> 16) & 1u);
  return (u16)(u >> 16);
}
__device__ __forceinline__ float b2f(u16 b) { return __uint_as_float(((unsigned int)b) << 16); }

__device__ __forceinline__ bf16x8 pack8(const float* p) { // 8 consecutive f32 -> bf16x8
  float4 a = *(const float4*)p;
  float4 b = *(const float4*)(p + 4);
  bf16x8 r;
  r[0] = (short)f2b(a.x); r[1] = (short)f2b(a.y); r[2] = (short)f2b(a.z); r[3] = (short)f2b(a.w);
  r[4] = (short)f2b(b.x); r[5] = (short)f2b(b.y); r[6] = (short)f2b(b.z); r[7] = (short)f2b(b.w);
  return r;
}

// acquire load, device scope: cross-XCD-safe read of atomically-accumulated data
__device__ __forceinline__ float aql(const float* p) {
  return __hip_atomic_load(p, __ATOMIC_ACQUIRE, __HIP_MEMORY_SCOPE_AGENT);
}

// ---- kA: K/V projection + exp + context/S accumulation (round-4 verified body),
//      plus a LAST-BLOCK TAIL: the block drawing done-ticket 511 sees all other
//      blocks' atomics (acq-rel ticket + fences), stages ctx for both batches
//      into LDS, emits context_last + CLS_out, and builds mfrag (M = Wr*ctx in
//      MFMA A-frag layout) ONCE for kB. No spins: blocks that aren't last exit.
__global__ __launch_bounds__(256) void kA(
    const float* __restrict__ x, const float* __restrict__ CLS,
    const float* __restrict__ Wk, const float* __restrict__ bk,
    const float* __restrict__ Wv, const float* __restrict__ bv,
    const float* __restrict__ Wr, float* __restrict__ S2,
    float* __restrict__ Cnum2, unsigned int* __restrict__ done,
    u16* __restrict__ mfrag, float* __restrict__ out) {
  __shared__ __align__(16) u16 xT[64][136];     // [l][ch] bf16
  __shared__ __align__(16) u16 ev[256][72];     // rows 0..127 E, 128..255 V; tail: ctxn f32[4096]
  __shared__ unsigned int lastflag;
  const int t = threadIdx.x;
  const int w = t >> 6, lane = t & 63;
  const int quad = lane >> 4, lm = lane & 15;
  const int bid = blockIdx.x;
  const int n = bid >> 8;                       // 512 blocks: 256 per batch
  const int l0base = (bid & 255) << 8;          // 256 cols per block
  const int slot = bid & 3;                     // 4 atomic slots
  const int sc = t >> 4, sl4 = t & 15;

  float4 pf[8];
  #pragma unroll
  for (int i = 0; i < 8; ++i)
    pf[i] = *(const float4*)(x + (((size_t)(n * 128 + sc * 8 + i)) << 16) + l0base + sl4 * 4);

  // W fragments as MFMA B-operand: nt 0,1 = Wk rows {w*32, w*32+16}+lm; nt 2,3 = Wv
  bf16x8 wf[4][4];
  #pragma unroll
  for (int nt = 0; nt < 4; ++nt) {
    const float* W = (nt < 2) ? Wk : Wv;
    int row = w * 32 + (nt & 1) * 16 + lm;
    #pragma unroll
    for (int ks = 0; ks < 4; ++ks)
      wf[nt][ks] = pack8(W + row * 128 + ks * 32 + quad * 8);
  }
  float biasE[2] = { bk[w * 32 + lm], bk[w * 32 + 16 + lm] };
  float biasV[2] = { bv[w * 32 + lm], bv[w * 32 + 16 + lm] };

  floatx4 z4 = {0.f, 0.f, 0.f, 0.f};
  floatx4 cacc[2] = {z4, z4};                   // context acc (2 heads per wave)
  float sacc[2] = {0.f, 0.f};                   // S partials, lane-local

  for (int tile = 0; tile < 4; ++tile) {
    const float* pff = (const float*)pf;
    #pragma unroll
    for (int r = 0; r < 4; ++r) {
      bf16x8 vx;
      #pragma unroll
      for (int i = 0; i < 8; ++i) vx[i] = (short)f2b(pff[i * 4 + r]);
      *(bf16x8*)&xT[sl4 * 4 + r][sc * 8] = vx;  // ds_write_b128
    }
    if (tile < 3) {
      int l0n = l0base + (tile + 1) * 64;
      #pragma unroll
      for (int i = 0; i < 8; ++i)
        pf[i] = *(const float4*)(x + (((size_t)(n * 128 + sc * 8 + i)) << 16) + l0n + sl4 * 4);
    }
    __syncthreads();                            // A: xT ready

    floatx4 acc[4][4];
    #pragma unroll
    for (int mt = 0; mt < 4; ++mt)
      #pragma unroll
      for (int nt = 0; nt < 4; ++nt) acc[mt][nt] = z4;

    #pragma unroll
    for (int mt = 0; mt < 4; ++mt)
      #pragma unroll
      for (int ks = 0; ks < 4; ++ks) {
        bf16x8 xa = *(const bf16x8*)&xT[mt * 16 + lm][ks * 32 + quad * 8];
        #pragma unroll
        for (int nt = 0; nt < 4; ++nt)
          acc[mt][nt] = __builtin_amdgcn_mfma_f32_16x16x32_bf16(xa, wf[nt][ks], acc[mt][nt], 0, 0, 0);
      }
    __syncthreads();                            // B: xT consumed, next stores safe

    // epilogue: D[m=l][n=ch]; ch = w*32+nt*16+lm, l = mt*16+quad*4+j -> b64 writes
    #pragma unroll
    for (int nt = 0; nt < 2; ++nt)
      #pragma unroll
      for (int mt = 0; mt < 4; ++mt) {
        short4v p;
        #pragma unroll
        for (int j = 0; j < 4; ++j) {
          float v = __expf(acc[mt][nt][j] + biasE[nt]);
          u16 b = f2b(v);
          sacc[nt] += b2f(b);
          p[j] = (short)b;
        }
        *(short4v*)&ev[w * 32 + nt * 16 + lm][mt * 16 + quad * 4] = p;
      }
    #pragma unroll
    for (int nt = 0; nt < 2; ++nt)
      #pragma unroll
      for (int mt = 0; mt < 4; ++mt) {
        short4v p;
        #pragma unroll
        for (int j = 0; j < 4; ++j)
          p[j] = (short)f2b(acc[mt][nt + 2][j] + biasV[nt]);
        *(short4v*)&ev[128 + w * 32 + nt * 16 + lm][mt * 16 + quad * 4] = p;
      }

    // context MFMAs: read ONLY this wave's own ev rows (same-wave DS order)
    #pragma unroll
    for (int hh = 0; hh < 2; ++hh) {
      int h = w * 2 + hh;
      #pragma unroll
      for (int ks = 0; ks < 2; ++ks) {
        bf16x8 aE = *(const bf16x8*)&ev[h * 16 + lm][ks * 32 + quad * 8];
        bf16x8 bV = *(const bf16x8*)&ev[128 + h * 16 + lm][ks * 32 + quad * 8];
        cacc[hh] = __builtin_amdgcn_mfma_f32_16x16x32_bf16(aE, bV, cacc[hh], 0, 0, 0);
      }
    }
  }

  float* Cn = Cnum2 + slot * 4096;
  #pragma unroll
  for (int hh = 0; hh < 2; ++hh) {
    int h = w * 2 + hh;
    #pragma unroll
    for (int j = 0; j < 4; ++j)
      atomicAdd(&Cn[((n * 8 + h) * 16 + quad * 4 + j) * 16 + lm], cacc[hh][j]);
  }
  #pragma unroll
  for (int nt = 0; nt < 2; ++nt) {
    float s = sacc[nt];
    s += __shfl_xor(s, 16);
    s += __shfl_xor(s, 32);
    if (quad == 0)
      atomicAdd(&S2[slot * 256 + n * 128 + w * 32 + nt * 16 + lm], s);
  }

  // ---- done-ticket: last block runs the tail (ctx finalize + mfrag + outputs)
  __syncthreads();                              // all threads' atomics drained
  if (t == 0) {
    __threadfence();                            // release prior atomics
    unsigned int old = __hip_atomic_fetch_add(done, 1u, __ATOMIC_ACQ_REL, __HIP_MEMORY_SCOPE_AGENT);
    lastflag = (old == NBLK - 1) ? 1u : 0u;
  }
  __syncthreads();
  if (!lastflag) return;

  // ======================= last-block tail =======================
  float* ctxn = (float*)ev;                     // [nn*128 + h*16 + k][v] f32 (16 KB)
  {
    // thread t owns row r = t (nn = t>>7, hk = t&127): den + 16 v's
    float ek[4];
    float den = 0.f;
    #pragma unroll
    for (int j = 0; j < 4; ++j) {
      ek[j] = __expf(CLS[t * 4 + j]);
      den += ek[j];
    }
    #pragma unroll
    for (int s = 0; s < 4; ++s) den += aql(&S2[s * 256 + t]);
    float inv = 1.f / den;
    int nn = t >> 7;
    int hbase = (t & 127) & 0x70;               // h*16 within this n's 128 channels
    #pragma unroll
    for (int v = 0; v < 16; ++v) {
      float num = 0.f;
      #pragma unroll
      for (int s = 0; s < 4; ++s) num += aql(&Cnum2[s * 4096 + t * 16 + v]);
      #pragma unroll
      for (int j = 0; j < 4; ++j) num += ek[j] * CLS[(nn * 128 + hbase + v) * 4 + j];
      ctxn[t * 16 + v] = num * inv;
    }
  }
  __syncthreads();                              // ctxn ready

  // context_last: 512 values (head 7, both n)
  #pragma unroll
  for (int e = t; e < 512; e += 256)
    out[OUT_CTX + e] = ctxn[(((e >> 8) * 128 + 112 + ((e >> 4) & 15)) << 4) + (e & 15)];
  // CLS_out: 128 values
  if (t < 128) {
    int nn = t >> 6, vc = (t >> 2) & 15, j = t & 3;
    float den = 0.f, num = 0.f;
    #pragma unroll
    for (int kc = 0; kc < 16; ++kc) {
      float e_ = __expf(CLS[(nn * 128 + 112 + kc) * 4 + j]);
      den += e_;
      num += e_ * ctxn[((nn * 128 + 112 + kc) << 4) + vc];
    }
    out[OUT_CLS + t] = num / den;
  }

  // mfrag: A-frag-linear M = Wr * ctx_n, 2n x 8rb x 4ks x 64lane x 8j bf16
  for (int i = 0; i < 128; ++i) {
    int e = i * 256 + t;
    int nn = e >> 14;
    int rem = e & 16383;
    int rb = rem >> 11;
    int ks = (rem >> 9) & 3;
    int ln = (rem >> 3) & 63;
    int j = rem & 7;
    int o = rb * 16 + (ln & 15);
    int cc = ks * 32 + (ln >> 4) * 8 + j;
    int h = cc >> 4, k = cc & 15;
    const float* wp = Wr + o * 128 + h * 16;
    const float* cp = ctxn + ((nn * 128 + h * 16 + k) << 4);
    float m = 0.f;
    #pragma unroll
    for (int v = 0; v < 16; ++v) m += wp[v] * cp[v];
    mfrag[e] = f2b(m);
  }
}

// ---- kB: out = M * softmax_q(Wq x + bq) + br. 512 blocks x 4 tiles of 64 cols.
//      No prologue beyond frag loads: mA comes precomputed from kA's tail.
//      LDS = xT + qT = 34816 B. Plain launch_bounds (round-3's (256,4) spilled).
__global__ __launch_bounds__(256) void kB(
    const float* __restrict__ x, const float* __restrict__ Wq,
    const float* __restrict__ bq, const float* __restrict__ br,
    const u16* __restrict__ mfrag, float* __restrict__ out) {
  __shared__ __align__(16) u16 xT[64][136];     // [l][ch] bf16
  __shared__ __align__(16) u16 qT[64][136];     // softmaxed queries, [l][ch] bf16
  const int t = threadIdx.x;
  const int w = t >> 6, lane = t & 63;
  const int quad = lane >> 4, lm = lane & 15;
  const int bid = blockIdx.x;
  const int n = bid >> 8;                       // 512 blocks: 256 per batch
  const int l0base = (bid & 255) << 8;          // 256 cols per block
  const int sc = t >> 4, sl4 = t & 15;

  float4 pf[8];
  #pragma unroll
  for (int i = 0; i < 8; ++i)
    pf[i] = *(const float4*)(x + (((size_t)(n * 128 + sc * 8 + i)) << 16) + l0base + sl4 * 4);

  bf16x8 wq[2][4], mA[2][4];
  #pragma unroll
  for (int mt = 0; mt < 2; ++mt) {
    int row = (w * 2 + mt) * 16 + lm;
    #pragma unroll
    for (int ks = 0; ks < 4; ++ks) {
      wq[mt][ks] = pack8(Wq + row * 128 + ks * 32 + quad * 8);
      mA[mt][ks] = *(const bf16x8*)(mfrag + ((((n * 8 + w * 2 + mt) * 4 + ks) * 64 + lane) * 8));
    }
  }
  float bqv[2][4], brv[2][4];
  #pragma unroll
  for (int mt = 0; mt < 2; ++mt)
    #pragma unroll
    for (int j = 0; j < 4; ++j) {
      bqv[mt][j] = bq[(w * 2 + mt) * 16 + quad * 4 + j];
      brv[mt][j] = br[(w * 2 + mt) * 16 + quad * 4 + j];
    }

  floatx4 z4 = {0.f, 0.f, 0.f, 0.f};
  for (int tile = 0; tile < 4; ++tile) {
    int l0 = l0base + tile * 64;
    const float* pff = (const float*)pf;
    #pragma unroll
    for (int r = 0; r < 4; ++r) {
      bf16x8 vx;
      #pragma unroll
      for (int i = 0; i < 8; ++i) vx[i] = (short)f2b(pff[i * 4 + r]);
      *(bf16x8*)&xT[sl4 * 4 + r][sc * 8] = vx;
    }
    if (tile < 3) {
      int l0n = l0base + (tile + 1) * 64;
      #pragma unroll
      for (int i = 0; i < 8; ++i)
        pf[i] = *(const float4*)(x + (((size_t)(n * 128 + sc * 8 + i)) << 16) + l0n + sl4 * 4);
    }
    __syncthreads();                            // A: xT RAW + qT WAR

    floatx4 acc[2][4];
    #pragma unroll
    for (int mt = 0; mt < 2; ++mt)
      #pragma unroll
      for (int nt = 0; nt < 4; ++nt) acc[mt][nt] = z4;

    #pragma unroll
    for (int nt = 0; nt < 4; ++nt)
      #pragma unroll
      for (int ks = 0; ks < 4; ++ks) {
        bf16x8 b = *(const bf16x8*)&xT[nt * 16 + lm][ks * 32 + quad * 8];
        #pragma unroll
        for (int mt = 0; mt < 2; ++mt)
          acc[mt][nt] = __builtin_amdgcn_mfma_f32_16x16x32_bf16(wq[mt][ks], b, acc[mt][nt], 0, 0, 0);
      }

    // per-column softmax over the 16 channels of each head (wave-local)
    #pragma unroll
    for (int mt = 0; mt < 2; ++mt) {
      int h = w * 2 + mt;
      #pragma unroll
      for (int nt = 0; nt < 4; ++nt) {
        float e[4];
        float ssum = 0.f;
        #pragma unroll
        for (int j = 0; j < 4; ++j) {
          e[j] = __expf(acc[mt][nt][j] + bqv[mt][j]);
          ssum += e[j];
        }
        ssum += __shfl_xor(ssum, 16);
        ssum += __shfl_xor(ssum, 32);
        float inv = 1.f / ssum;
        short4v p;
        #pragma unroll
        for (int j = 0; j < 4; ++j) p[j] = (short)f2b(e[j] * inv);
        *(short4v*)&qT[nt * 16 + lm][h * 16 + quad * 4] = p;
      }
    }
    __syncthreads();                            // B: all heads' q channels ready

    floatx4 acc2[2][4];
    #pragma unroll
    for (int mt = 0; mt < 2; ++mt)
      #pragma unroll
      for (int nt = 0; nt < 4; ++nt) acc2[mt][nt] = z4;

    #pragma unroll
    for (int nt = 0; nt < 4; ++nt)
      #pragma unroll
      for (int ks = 0; ks < 4; ++ks) {
        bf16x8 b = *(const bf16x8*)&qT[nt * 16 + lm][ks * 32 + quad * 8];
        #pragma unroll
        for (int mt = 0; mt < 2; ++mt)
          acc2[mt][nt] = __builtin_amdgcn_mfma_f32_16x16x32_bf16(mA[mt][ks], b, acc2[mt][nt], 0, 0, 0);
      }

    #pragma unroll
    for (int mt = 0; mt < 2; ++mt)
      #pragma unroll
      for (int j = 0; j < 4; ++j) {
        int R = (w * 2 + mt) * 16 + quad * 4 + j;
        #pragma unroll
        for (int nt = 0; nt < 4; ++nt)
          out[(((size_t)(n * 128 + R)) << 16) + l0 + nt * 16 + lm] = acc2[mt][nt][j] + brv[mt][j];
      }
  }
}

extern "C" void kernel_launch(void* const* d_in, const int* in_sizes, int n_in,
                              void* d_out, int out_size, void* d_ws, size_t ws_size,
                              hipStream_t stream) {
  const float* x   = (const float*)d_in[0];
  const float* CLS = (const float*)d_in[1];
  const float* Wk  = (const float*)d_in[2];
  const float* bk  = (const float*)d_in[3];
  const float* Wq  = (const float*)d_in[4];
  const float* bq  = (const float*)d_in[5];
  const float* Wv  = (const float*)d_in[6];
  const float* bv  = (const float*)d_in[7];
  const float* Wr  = (const float*)d_in[8];
  const float* br  = (const float*)d_in[9];
  float* out = (float*)d_out;
  char* ws = (char*)d_ws;
  float* S2          = (float*)(ws + 0);            // 4 slots x 256 f32  = 4096 B
  float* Cnum2       = (float*)(ws + 4096);         // 4 slots x 4096 f32 = 65536 B
  unsigned int* done = (unsigned int*)(ws + 69632); // ticket counter (4 B)
  u16* mfrag         = (u16*)(ws + 69696);          // 2*8*4*64*8 bf16 = 65536 B (16B-aligned)

  hipMemsetAsync(ws, 0, 69696, stream);             // accumulators + ticket
  kA<<<NBLK, 256, 0, stream>>>(x, CLS, Wk, bk, Wv, bv, Wr, S2, Cnum2, done, mfrag, out);
  kB<<<512, 256, 0, stream>>>(x, Wq, bq, br, mfrag, out);
}

// Round 7
// 229.955 us; speedup vs baseline: 1.0361x; 1.0361x over previous
//
#include <hip/hip_runtime.h>

typedef unsigned short u16;
typedef short bf16x8 __attribute__((ext_vector_type(8)));
typedef short short4v __attribute__((ext_vector_type(4)));
typedef float floatx4 __attribute__((ext_vector_type(4)));

#define OUT_CTX 16777216           // 2*128*65536 attention elems
#define OUT_CLS (OUT_CTX + 512)
#define NBLK 512

__device__ __forceinline__ u16 f2b(float f) {           // fp32 -> bf16 RNE
  unsigned int u = __float_as_uint(f);
  u += 0x7fffu + ((u >> 16) & 1u);
  return (u16)(u >> 16);
}
__device__ __forceinline__ float b2f(u16 b) { return __uint_as_float(((unsigned int)b) << 16); }

__device__ __forceinline__ bf16x8 pack8(const float* p) { // 8 consecutive f32 -> bf16x8
  float4 a = *(const float4*)p;
  float4 b = *(const float4*)(p + 4);
  bf16x8 r;
  r[0] = (short)f2b(a.x); r[1] = (short)f2b(a.y); r[2] = (short)f2b(a.z); r[3] = (short)f2b(a.w);
  r[4] = (short)f2b(b.x); r[5] = (short)f2b(b.y); r[6] = (short)f2b(b.z); r[7] = (short)f2b(b.w);
  return r;
}

// acquire load, device scope: cross-XCD-safe read of atomically-accumulated data
__device__ __forceinline__ float aql(const float* p) {
  return __hip_atomic_load(p, __ATOMIC_ACQUIRE, __HIP_MEMORY_SCOPE_AGENT);
}

// ---- kA: K/V projection + exp + context/S accumulation.
//      512 blocks x 4 tiles. ONE barrier per tile: xT double-buffered (kills the
//      WAR barrier); ev rows are wave-local for both write and ctx-MFMA read.
//      Also streams the transposed bf16 x-tiles to xbf (kB's cheap input).
//      Last block (done-ticket) runs the tail: Wr staged to LDS as bf16 (round-6
//      tail did 2048 scalar GLOBAL Wr loads/thread on one CU -> ~50us serial),
//      ctx finalize, context_last + CLS_out, mfrag build — all-LDS, ~4us.
__global__ __launch_bounds__(256) void kA(
    const float* __restrict__ x, const float* __restrict__ CLS,
    const float* __restrict__ Wk, const float* __restrict__ bk,
    const float* __restrict__ Wv, const float* __restrict__ bv,
    const float* __restrict__ Wr, float* __restrict__ S2,
    float* __restrict__ Cnum2, unsigned int* __restrict__ done,
    u16* __restrict__ mfrag, u16* __restrict__ xbf, float* __restrict__ out) {
  __shared__ __align__(16) u16 xT2[2][64][136];  // double-buffered x tile (34816 B)
  __shared__ __align__(16) u16 ev[256][72];      // E/V (36864 B); tail: ctxn f32[4096]
  __shared__ unsigned int lastflag;
  const int t = threadIdx.x;
  const int w = t >> 6, lane = t & 63;
  const int quad = lane >> 4, lm = lane & 15;
  const int bid = blockIdx.x;
  const int n = bid >> 8;                       // 512 blocks: 256 per batch
  const int l0base = (bid & 255) << 8;          // 256 cols per block
  const int slot = bid & 3;                     // 4 atomic slots
  const int sc = t >> 4, sl4 = t & 15;

  float4 pf[8];
  #pragma unroll
  for (int i = 0; i < 8; ++i)
    pf[i] = *(const float4*)(x + (((size_t)(n * 128 + sc * 8 + i)) << 16) + l0base + sl4 * 4);

  // W fragments as MFMA B-operand: nt 0,1 = Wk rows {w*32, w*32+16}+lm; nt 2,3 = Wv
  bf16x8 wf[4][4];
  #pragma unroll
  for (int nt = 0; nt < 4; ++nt) {
    const float* W = (nt < 2) ? Wk : Wv;
    int row = w * 32 + (nt & 1) * 16 + lm;
    #pragma unroll
    for (int ks = 0; ks < 4; ++ks)
      wf[nt][ks] = pack8(W + row * 128 + ks * 32 + quad * 8);
  }
  float biasE[2] = { bk[w * 32 + lm], bk[w * 32 + 16 + lm] };
  float biasV[2] = { bv[w * 32 + lm], bv[w * 32 + 16 + lm] };

  floatx4 z4 = {0.f, 0.f, 0.f, 0.f};
  floatx4 cacc[2] = {z4, z4};                   // context acc (2 heads per wave)
  float sacc[2] = {0.f, 0.f};                   // S partials, lane-local

  for (int tile = 0; tile < 4; ++tile) {
    int l0 = l0base + tile * 64;
    u16 (*xb)[136] = xT2[tile & 1];
    const float* pff = (const float*)pf;
    #pragma unroll
    for (int r = 0; r < 4; ++r) {
      bf16x8 vx;
      #pragma unroll
      for (int i = 0; i < 8; ++i) vx[i] = (short)f2b(pff[i * 4 + r]);
      *(bf16x8*)&xb[sl4 * 4 + r][sc * 8] = vx;  // ds_write_b128
      // stream transposed bf16 x to workspace for kB (same registers, 16B store)
      *(bf16x8*)(xbf + ((((size_t)n << 16) + l0 + sl4 * 4 + r) << 7) + sc * 8) = vx;
    }
    if (tile < 3) {
      int l0n = l0base + (tile + 1) * 64;
      #pragma unroll
      for (int i = 0; i < 8; ++i)
        pf[i] = *(const float4*)(x + (((size_t)(n * 128 + sc * 8 + i)) << 16) + l0n + sl4 * 4);
      __builtin_amdgcn_sched_barrier(0);        // pin prefetch issue point
    }
    __syncthreads();                            // the ONLY barrier per tile (xb RAW;
                                                // also orders next-next stage WAR)

    floatx4 acc[4][4];
    #pragma unroll
    for (int mt = 0; mt < 4; ++mt)
      #pragma unroll
      for (int nt = 0; nt < 4; ++nt) acc[mt][nt] = z4;

    #pragma unroll
    for (int mt = 0; mt < 4; ++mt)
      #pragma unroll
      for (int ks = 0; ks < 4; ++ks) {
        bf16x8 xa = *(const bf16x8*)&xb[mt * 16 + lm][ks * 32 + quad * 8];
        #pragma unroll
        for (int nt = 0; nt < 4; ++nt)
          acc[mt][nt] = __builtin_amdgcn_mfma_f32_16x16x32_bf16(xa, wf[nt][ks], acc[mt][nt], 0, 0, 0);
      }

    // epilogue: D[m=l][n=ch]; ev rows are wave-owned -> no barrier around this
    #pragma unroll
    for (int nt = 0; nt < 2; ++nt)
      #pragma unroll
      for (int mt = 0; mt < 4; ++mt) {
        short4v p;
        #pragma unroll
        for (int j = 0; j < 4; ++j) {
          float v = __expf(acc[mt][nt][j] + biasE[nt]);
          u16 b = f2b(v);
          sacc[nt] += b2f(b);
          p[j] = (short)b;
        }
        *(short4v*)&ev[w * 32 + nt * 16 + lm][mt * 16 + quad * 4] = p;
      }
    #pragma unroll
    for (int nt = 0; nt < 2; ++nt)
      #pragma unroll
      for (int mt = 0; mt < 4; ++mt) {
        short4v p;
        #pragma unroll
        for (int j = 0; j < 4; ++j)
          p[j] = (short)f2b(acc[mt][nt + 2][j] + biasV[nt]);
        *(short4v*)&ev[128 + w * 32 + nt * 16 + lm][mt * 16 + quad * 4] = p;
      }

    // context MFMAs: read ONLY this wave's own ev rows (same-wave DS order)
    #pragma unroll
    for (int hh = 0; hh < 2; ++hh) {
      int h = w * 2 + hh;
      #pragma unroll
      for (int ks = 0; ks < 2; ++ks) {
        bf16x8 aE = *(const bf16x8*)&ev[h * 16 + lm][ks * 32 + quad * 8];
        bf16x8 bV = *(const bf16x8*)&ev[128 + h * 16 + lm][ks * 32 + quad * 8];
        cacc[hh] = __builtin_amdgcn_mfma_f32_16x16x32_bf16(aE, bV, cacc[hh], 0, 0, 0);
      }
    }
  }

  float* Cn = Cnum2 + slot * 4096;
  #pragma unroll
  for (int hh = 0; hh < 2; ++hh) {
    int h = w * 2 + hh;
    #pragma unroll
    for (int j = 0; j < 4; ++j)
      atomicAdd(&Cn[((n * 8 + h) * 16 + quad * 4 + j) * 16 + lm], cacc[hh][j]);
  }
  #pragma unroll
  for (int nt = 0; nt < 2; ++nt) {
    float s = sacc[nt];
    s += __shfl_xor(s, 16);
    s += __shfl_xor(s, 32);
    if (quad == 0)
      atomicAdd(&S2[slot * 256 + n * 128 + w * 32 + nt * 16 + lm], s);
  }

  // ---- done-ticket: last block runs the tail
  __syncthreads();
  if (t == 0) {
    __threadfence();
    unsigned int old = __hip_atomic_fetch_add(done, 1u, __ATOMIC_ACQ_REL, __HIP_MEMORY_SCOPE_AGENT);
    lastflag = (old == NBLK - 1) ? 1u : 0u;
  }
  __syncthreads();
  if (!lastflag) return;

  // ======================= last-block tail (all-LDS) =======================
  // stage Wr as bf16 into LDS (reuse xT2: 32768 B <= 34816)
  u16* wrl = (u16*)xT2;
  #pragma unroll
  for (int i = 0; i < 8; ++i) {
    int idx = (i * 256 + t) * 8;                // 16384 f32 -> bf16, coalesced
    *(bf16x8*)&wrl[idx] = pack8(Wr + idx);
  }
  // ctx finalize into ev region
  float* ctxn = (float*)ev;                     // [nn*128 + h*16 + k][v] f32 (16 KB)
  {
    float ek[4];
    float den = 0.f;
    #pragma unroll
    for (int j = 0; j < 4; ++j) {
      ek[j] = __expf(CLS[t * 4 + j]);
      den += ek[j];
    }
    #pragma unroll
    for (int s = 0; s < 4; ++s) den += aql(&S2[s * 256 + t]);
    float inv = 1.f / den;
    int nn = t >> 7;
    int hbase = (t & 127) & 0x70;
    #pragma unroll
    for (int v = 0; v < 16; ++v) {
      float num = 0.f;
      #pragma unroll
      for (int s = 0; s < 4; ++s) num += aql(&Cnum2[s * 4096 + t * 16 + v]);
      #pragma unroll
      for (int j = 0; j < 4; ++j) num += ek[j] * CLS[(nn * 128 + hbase + v) * 4 + j];
      ctxn[t * 16 + v] = num * inv;
    }
  }
  __syncthreads();                              // wrl + ctxn ready

  // context_last: 512 values (head 7, both n)
  #pragma unroll
  for (int e = t; e < 512; e += 256)
    out[OUT_CTX + e] = ctxn[(((e >> 8) * 128 + 112 + ((e >> 4) & 15)) << 4) + (e & 15)];
  // CLS_out: 128 values
  if (t < 128) {
    int nn = t >> 6, vc = (t >> 2) & 15, j = t & 3;
    float den = 0.f, num = 0.f;
    #pragma unroll
    for (int kc = 0; kc < 16; ++kc) {
      float e_ = __expf(CLS[(nn * 128 + 112 + kc) * 4 + j]);
      den += e_;
      num += e_ * ctxn[((nn * 128 + 112 + kc) << 4) + vc];
    }
    out[OUT_CLS + t] = num / den;
  }

  // mfrag: A-frag-linear M = Wr * ctx_n (reads Wr from LDS, ctx from LDS)
  for (int i = 0; i < 128; ++i) {
    int e = i * 256 + t;
    int nn = e >> 14;
    int rem = e & 16383;
    int rb = rem >> 11;
    int ks = (rem >> 9) & 3;
    int ln = (rem >> 3) & 63;
    int j = rem & 7;
    int o = rb * 16 + (ln & 15);
    int cc = ks * 32 + (ln >> 4) * 8 + j;
    int h = cc >> 4, k = cc & 15;
    const u16* wp = wrl + o * 128 + h * 16;
    const float* cp = ctxn + ((nn * 128 + h * 16 + k) << 4);
    bf16x8 w0 = *(const bf16x8*)wp;
    bf16x8 w1 = *(const bf16x8*)(wp + 8);
    float m = 0.f;
    #pragma unroll
    for (int v = 0; v < 8; ++v) m += b2f((u16)w0[v]) * cp[v];
    #pragma unroll
    for (int v = 0; v < 8; ++v) m += b2f((u16)w1[v]) * cp[8 + v];
    mfrag[e] = f2b(m);
  }
}

// ---- kB: out = M * softmax_q(Wq xbf + bq) + br. 512 blocks x 4 tiles.
//      Stages from kA's transposed bf16 xbf: 4 x 16B loads + 4 ds_writes per
//      thread per tile, ZERO conversions (was 8 f32 loads + 32 cvt). mA
//      precomputed (kA tail). Numerically identical to round 6 (same f2b(x)).
__global__ __launch_bounds__(256) void kB(
    const u16* __restrict__ xbf, const float* __restrict__ Wq,
    const float* __restrict__ bq, const float* __restrict__ br,
    const u16* __restrict__ mfrag, float* __restrict__ out) {
  __shared__ __align__(16) u16 xT[64][136];     // [l][ch] bf16
  __shared__ __align__(16) u16 qT[64][136];     // softmaxed queries
  const int t = threadIdx.x;
  const int w = t >> 6, lane = t & 63;
  const int quad = lane >> 4, lm = lane & 15;
  const int bid = blockIdx.x;
  const int n = bid >> 8;                       // 512 blocks: 256 per batch
  const int l0base = (bid & 255) << 8;          // 256 cols per block
  const int sl = t >> 2;                        // staging: l row 0..63
  const int scq = t & 3;                        // 64B ch-chunk

  bf16x8 pfb[4];
  #pragma unroll
  for (int k = 0; k < 4; ++k)
    pfb[k] = *(const bf16x8*)(xbf + ((((size_t)n << 16) + l0base + sl) << 7) + scq * 32 + k * 8);

  bf16x8 wq[2][4], mA[2][4];
  #pragma unroll
  for (int mt = 0; mt < 2; ++mt) {
    int row = (w * 2 + mt) * 16 + lm;
    #pragma unroll
    for (int ks = 0; ks < 4; ++ks) {
      wq[mt][ks] = pack8(Wq + row * 128 + ks * 32 + quad * 8);
      mA[mt][ks] = *(const bf16x8*)(mfrag + ((((n * 8 + w * 2 + mt) * 4 + ks) * 64 + lane) * 8));
    }
  }
  float bqv[2][4], brv[2][4];
  #pragma unroll
  for (int mt = 0; mt < 2; ++mt)
    #pragma unroll
    for (int j = 0; j < 4; ++j) {
      bqv[mt][j] = bq[(w * 2 + mt) * 16 + quad * 4 + j];
      brv[mt][j] = br[(w * 2 + mt) * 16 + quad * 4 + j];
    }

  floatx4 z4 = {0.f, 0.f, 0.f, 0.f};
  for (int tile = 0; tile < 4; ++tile) {
    int l0 = l0base + tile * 64;
    #pragma unroll
    for (int k = 0; k < 4; ++k)
      *(bf16x8*)&xT[sl][scq * 32 + k * 8] = pfb[k];
    if (tile < 3) {
      int l0n = l0base + (tile + 1) * 64;
      #pragma unroll
      for (int k = 0; k < 4; ++k)
        pfb[k] = *(const bf16x8*)(xbf + ((((size_t)n << 16) + l0n + sl) << 7) + scq * 32 + k * 8);
      __builtin_amdgcn_sched_barrier(0);        // pin prefetch issue point
    }
    __syncthreads();                            // A: xT RAW + qT WAR

    floatx4 acc[2][4];
    #pragma unroll
    for (int mt = 0; mt < 2; ++mt)
      #pragma unroll
      for (int nt = 0; nt < 4; ++nt) acc[mt][nt] = z4;

    #pragma unroll
    for (int nt = 0; nt < 4; ++nt)
      #pragma unroll
      for (int ks = 0; ks < 4; ++ks) {
        bf16x8 b = *(const bf16x8*)&xT[nt * 16 + lm][ks * 32 + quad * 8];
        #pragma unroll
        for (int mt = 0; mt < 2; ++mt)
          acc[mt][nt] = __builtin_amdgcn_mfma_f32_16x16x32_bf16(wq[mt][ks], b, acc[mt][nt], 0, 0, 0);
      }

    // per-column softmax over the 16 channels of each head (wave-local)
    #pragma unroll
    for (int mt = 0; mt < 2; ++mt) {
      int h = w * 2 + mt;
      #pragma unroll
      for (int nt = 0; nt < 4; ++nt) {
        float e[4];
        float ssum = 0.f;
        #pragma unroll
        for (int j = 0; j < 4; ++j) {
          e[j] = __expf(acc[mt][nt][j] + bqv[mt][j]);
          ssum += e[j];
        }
        ssum += __shfl_xor(ssum, 16);
        ssum += __shfl_xor(ssum, 32);
        float inv = 1.f / ssum;
        short4v p;
        #pragma unroll
        for (int j = 0; j < 4; ++j) p[j] = (short)f2b(e[j] * inv);
        *(short4v*)&qT[nt * 16 + lm][h * 16 + quad * 4] = p;
      }
    }
    __syncthreads();                            // B: all heads' q channels ready

    floatx4 acc2[2][4];
    #pragma unroll
    for (int mt = 0; mt < 2; ++mt)
      #pragma unroll
      for (int nt = 0; nt < 4; ++nt) acc2[mt][nt] = z4;

    #pragma unroll
    for (int nt = 0; nt < 4; ++nt)
      #pragma unroll
      for (int ks = 0; ks < 4; ++ks) {
        bf16x8 b = *(const bf16x8*)&qT[nt * 16 + lm][ks * 32 + quad * 8];
        #pragma unroll
        for (int mt = 0; mt < 2; ++mt)
          acc2[mt][nt] = __builtin_amdgcn_mfma_f32_16x16x32_bf16(mA[mt][ks], b, acc2[mt][nt], 0, 0, 0);
      }

    #pragma unroll
    for (int mt = 0; mt < 2; ++mt)
      #pragma unroll
      for (int j = 0; j < 4; ++j) {
        int R = (w * 2 + mt) * 16 + quad * 4 + j;
        #pragma unroll
        for (int nt = 0; nt < 4; ++nt)
          out[(((size_t)(n * 128 + R)) << 16) + l0 + nt * 16 + lm] = acc2[mt][nt][j] + brv[mt][j];
      }
  }
}

extern "C" void kernel_launch(void* const* d_in, const int* in_sizes, int n_in,
                              void* d_out, int out_size, void* d_ws, size_t ws_size,
                              hipStream_t stream) {
  const float* x   = (const float*)d_in[0];
  const float* CLS = (const float*)d_in[1];
  const float* Wk  = (const float*)d_in[2];
  const float* bk  = (const float*)d_in[3];
  const float* Wq  = (const float*)d_in[4];
  const float* bq  = (const float*)d_in[5];
  const float* Wv  = (const float*)d_in[6];
  const float* bv  = (const float*)d_in[7];
  const float* Wr  = (const float*)d_in[8];
  const float* br  = (const float*)d_in[9];
  float* out = (float*)d_out;
  char* ws = (char*)d_ws;
  float* S2          = (float*)(ws + 0);            // 4 slots x 256 f32  = 4096 B
  float* Cnum2       = (float*)(ws + 4096);         // 4 slots x 4096 f32 = 65536 B
  unsigned int* done = (unsigned int*)(ws + 69632); // ticket counter
  u16* mfrag         = (u16*)(ws + 69696);          // 65536 B
  u16* xbf           = (u16*)(ws + 135232);         // 2*65536*128 bf16 = 33.55 MB

  hipMemsetAsync(ws, 0, 69696, stream);             // accumulators + ticket
  kA<<<NBLK, 256, 0, stream>>>(x, CLS, Wk, bk, Wv, bv, Wr, S2, Cnum2, done, mfrag, xbf, out);
  kB<<<512, 256, 0, stream>>>(xbf, Wq, bq, br, mfrag, out);
}

// Round 8
// 179.076 us; speedup vs baseline: 1.3305x; 1.2841x over previous
//
#include <hip/hip_runtime.h>

typedef unsigned short u16;
typedef short bf16x8 __attribute__((ext_vector_type(8)));
typedef short short4v __attribute__((ext_vector_type(4)));
typedef float floatx4 __attribute__((ext_vector_type(4)));

#define OUT_CTX 16777216           // 2*128*65536 attention elems
#define OUT_CLS (OUT_CTX + 512)

__device__ __forceinline__ u16 f2b(float f) {           // fp32 -> bf16 RNE
  unsigned int u = __float_as_uint(f);
  u += 0x7fffu + ((u >> 16) & 1u);
  return (u16)(u >> 16);
}
__device__ __forceinline__ float b2f(u16 b) { return __uint_as_float(((unsigned int)b) << 16); }

__device__ __forceinline__ bf16x8 pack8(const float* p) { // 8 consecutive f32 -> bf16x8
  float4 a = *(const float4*)p;
  float4 b = *(const float4*)(p + 4);
  bf16x8 r;
  r[0] = (short)f2b(a.x); r[1] = (short)f2b(a.y); r[2] = (short)f2b(a.z); r[3] = (short)f2b(a.w);
  r[4] = (short)f2b(b.x); r[5] = (short)f2b(b.y); r[6] = (short)f2b(b.z); r[7] = (short)f2b(b.w);
  return r;
}

__device__ __forceinline__ float dot4(float4 a, float4 b) {
  return a.x * b.x + a.y * b.y + a.z * b.z + a.w * b.w;
}

// ---- kA: K/V projection + exp + context/S accumulation (round-4 verified body).
//      512 blocks x 4 tiles of 64 cols. Swapped GEMM1 (A = x-tile, B = W rows):
//      ev epilogue writes are ds_write_b64, S partials lane-local. Also streams
//      the transposed bf16 x-tiles to xbf (kB's cheap staging input).
//      NO serial tail (r6/r7 lesson: a one-block tail = ~55us of idle GPU).
__global__ __launch_bounds__(256) void kA(
    const float* __restrict__ x, const float* __restrict__ Wk,
    const float* __restrict__ bk, const float* __restrict__ Wv,
    const float* __restrict__ bv, float* __restrict__ S2,
    float* __restrict__ Cnum2, u16* __restrict__ xbf) {
  __shared__ __align__(16) u16 xT[64][136];     // [l][ch] bf16
  __shared__ __align__(16) u16 ev[256][72];     // rows 0..127 E, 128..255 V
  const int t = threadIdx.x;
  const int w = t >> 6, lane = t & 63;
  const int quad = lane >> 4, lm = lane & 15;
  const int bid = blockIdx.x;
  const int n = bid >> 8;                       // 512 blocks: 256 per batch
  const int l0base = (bid & 255) << 8;          // 256 cols per block
  const int slot = bid & 3;                     // 4 atomic slots
  const int sc = t >> 4, sl4 = t & 15;

  float4 pf[8];
  #pragma unroll
  for (int i = 0; i < 8; ++i)
    pf[i] = *(const float4*)(x + (((size_t)(n * 128 + sc * 8 + i)) << 16) + l0base + sl4 * 4);

  // W fragments as MFMA B-operand: nt 0,1 = Wk rows {w*32, w*32+16}+lm; nt 2,3 = Wv
  bf16x8 wf[4][4];
  #pragma unroll
  for (int nt = 0; nt < 4; ++nt) {
    const float* W = (nt < 2) ? Wk : Wv;
    int row = w * 32 + (nt & 1) * 16 + lm;
    #pragma unroll
    for (int ks = 0; ks < 4; ++ks)
      wf[nt][ks] = pack8(W + row * 128 + ks * 32 + quad * 8);
  }
  float biasE[2] = { bk[w * 32 + lm], bk[w * 32 + 16 + lm] };
  float biasV[2] = { bv[w * 32 + lm], bv[w * 32 + 16 + lm] };

  floatx4 z4 = {0.f, 0.f, 0.f, 0.f};
  floatx4 cacc[2] = {z4, z4};                   // context acc (2 heads per wave)
  float sacc[2] = {0.f, 0.f};                   // S partials, lane-local

  for (int tile = 0; tile < 4; ++tile) {
    int l0 = l0base + tile * 64;
    const float* pff = (const float*)pf;
    #pragma unroll
    for (int r = 0; r < 4; ++r) {
      bf16x8 vx;
      #pragma unroll
      for (int i = 0; i < 8; ++i) vx[i] = (short)f2b(pff[i * 4 + r]);
      *(bf16x8*)&xT[sl4 * 4 + r][sc * 8] = vx;  // ds_write_b128
      // stream transposed bf16 x to workspace for kB (same registers, 16B store)
      *(bf16x8*)(xbf + ((((size_t)n << 16) + l0 + sl4 * 4 + r) << 7) + sc * 8) = vx;
    }
    if (tile < 3) {
      int l0n = l0base + (tile + 1) * 64;
      #pragma unroll
      for (int i = 0; i < 8; ++i)
        pf[i] = *(const float4*)(x + (((size_t)(n * 128 + sc * 8 + i)) << 16) + l0n + sl4 * 4);
    }
    __syncthreads();                            // A: xT ready

    floatx4 acc[4][4];
    #pragma unroll
    for (int mt = 0; mt < 4; ++mt)
      #pragma unroll
      for (int nt = 0; nt < 4; ++nt) acc[mt][nt] = z4;

    #pragma unroll
    for (int mt = 0; mt < 4; ++mt)
      #pragma unroll
      for (int ks = 0; ks < 4; ++ks) {
        bf16x8 xa = *(const bf16x8*)&xT[mt * 16 + lm][ks * 32 + quad * 8];
        #pragma unroll
        for (int nt = 0; nt < 4; ++nt)
          acc[mt][nt] = __builtin_amdgcn_mfma_f32_16x16x32_bf16(xa, wf[nt][ks], acc[mt][nt], 0, 0, 0);
      }
    __syncthreads();                            // B: xT consumed, next stores safe

    // epilogue: D[m=l][n=ch]; ch = w*32+nt*16+lm, l = mt*16+quad*4+j -> b64 writes
    #pragma unroll
    for (int nt = 0; nt < 2; ++nt)
      #pragma unroll
      for (int mt = 0; mt < 4; ++mt) {
        short4v p;
        #pragma unroll
        for (int j = 0; j < 4; ++j) {
          float v = __expf(acc[mt][nt][j] + biasE[nt]);
          u16 b = f2b(v);
          sacc[nt] += b2f(b);
          p[j] = (short)b;
        }
        *(short4v*)&ev[w * 32 + nt * 16 + lm][mt * 16 + quad * 4] = p;
      }
    #pragma unroll
    for (int nt = 0; nt < 2; ++nt)
      #pragma unroll
      for (int mt = 0; mt < 4; ++mt) {
        short4v p;
        #pragma unroll
        for (int j = 0; j < 4; ++j)
          p[j] = (short)f2b(acc[mt][nt + 2][j] + biasV[nt]);
        *(short4v*)&ev[128 + w * 32 + nt * 16 + lm][mt * 16 + quad * 4] = p;
      }

    // context MFMAs: read ONLY this wave's own ev rows (same-wave DS order)
    #pragma unroll
    for (int hh = 0; hh < 2; ++hh) {
      int h = w * 2 + hh;
      #pragma unroll
      for (int ks = 0; ks < 2; ++ks) {
        bf16x8 aE = *(const bf16x8*)&ev[h * 16 + lm][ks * 32 + quad * 8];
        bf16x8 bV = *(const bf16x8*)&ev[128 + h * 16 + lm][ks * 32 + quad * 8];
        cacc[hh] = __builtin_amdgcn_mfma_f32_16x16x32_bf16(aE, bV, cacc[hh], 0, 0, 0);
      }
    }
  }

  float* Cn = Cnum2 + slot * 4096;
  #pragma unroll
  for (int hh = 0; hh < 2; ++hh) {
    int h = w * 2 + hh;
    #pragma unroll
    for (int j = 0; j < 4; ++j)
      atomicAdd(&Cn[((n * 8 + h) * 16 + quad * 4 + j) * 16 + lm], cacc[hh][j]);
  }
  #pragma unroll
  for (int nt = 0; nt < 2; ++nt) {
    float s = sacc[nt];
    s += __shfl_xor(s, 16);
    s += __shfl_xor(s, 32);
    if (quad == 0)
      atomicAdd(&S2[slot * 256 + n * 128 + w * 32 + nt * 16 + lm], s);
  }
}

// ---- kB: out = M * softmax_q(Wq xbf + bq) + br. 512 blocks x 4 tiles.
//      Round-4-verified PARALLEL prologue (plain loads — kernel boundary
//      guarantees visibility of kA's atomics): ctx finalize + CLS fold +
//      M-build per block (~10us total across the grid, vs ~55us serial tail).
//      Staging from kA's transposed bf16 xbf: zero conversions in the loop.
__global__ __launch_bounds__(256) void kB(
    const u16* __restrict__ xbf, const float* __restrict__ CLS,
    const float* __restrict__ Wq, const float* __restrict__ bq,
    const float* __restrict__ Wr, const float* __restrict__ br,
    const float* __restrict__ S2, const float* __restrict__ Cnum2,
    float* __restrict__ out) {
  __shared__ __align__(16) u16 xT[64][136];     // [l][ch] bf16, 17408 B
  __shared__ __align__(16) u16 ubuf[64 * 136];  // prologue: f32 ctxn[2048]; main: qT
  const int t = threadIdx.x;
  const int w = t >> 6, lane = t & 63;
  const int quad = lane >> 4, lm = lane & 15;
  const int bid = blockIdx.x;
  const int n = bid >> 8;                       // 512 blocks: 256 per batch
  const int l0base = (bid & 255) << 8;          // 256 cols per block
  const int sl = t >> 2;                        // staging: l row 0..63
  const int scq = t & 3;                        // 64B ch-chunk

  bf16x8 pfb[4];
  #pragma unroll
  for (int k = 0; k < 4; ++k)
    pfb[k] = *(const bf16x8*)(xbf + ((((size_t)n << 16) + l0base + sl) << 7) + scq * 32 + k * 8);

  bf16x8 wq[2][4];
  #pragma unroll
  for (int mt = 0; mt < 2; ++mt) {
    int row = (w * 2 + mt) * 16 + lm;
    #pragma unroll
    for (int ks = 0; ks < 4; ++ks)
      wq[mt][ks] = pack8(Wq + row * 128 + ks * 32 + quad * 8);
  }
  float bqv[2][4], brv[2][4];
  #pragma unroll
  for (int mt = 0; mt < 2; ++mt)
    #pragma unroll
    for (int j = 0; j < 4; ++j) {
      bqv[mt][j] = bq[(w * 2 + mt) * 16 + quad * 4 + j];
      brv[mt][j] = br[(w * 2 + mt) * 16 + quad * 4 + j];
    }

  // stage ctx = (sum Cnum slots + CLS num) / (sum S slots + CLS den) into LDS
  float* ctxn = (float*)ubuf;                   // [h*16+k][v] f32, this block's n
  {
    int hk = t >> 1, v0 = (t & 1) * 8;          // hk 0..127, v0 0 or 8
    int hbase = hk & 0x70;                      // h*16
    float ek[4];
    float den = 0.f;
    #pragma unroll
    for (int j = 0; j < 4; ++j) {
      ek[j] = __expf(CLS[(n * 128 + hk) * 4 + j]);
      den += ek[j];
    }
    #pragma unroll
    for (int s = 0; s < 4; ++s) den += S2[s * 256 + n * 128 + hk];
    float inv = 1.f / den;
    float vv[8];
    #pragma unroll
    for (int i = 0; i < 8; ++i) {
      int v = v0 + i;
      float num = 0.f;
      #pragma unroll
      for (int s = 0; s < 4; ++s) num += Cnum2[s * 4096 + (n * 128 + hk) * 16 + v];
      #pragma unroll
      for (int j = 0; j < 4; ++j) num += ek[j] * CLS[(n * 128 + hbase + v) * 4 + j];
      vv[i] = num * inv;
    }
    float4 a = {vv[0], vv[1], vv[2], vv[3]}, b = {vv[4], vv[5], vv[6], vv[7]};
    *(float4*)&ctxn[hk * 16 + v0] = a;
    *(float4*)&ctxn[hk * 16 + v0 + 4] = b;
  }
  __syncthreads();                              // ctxn ready

  // blocks 0 / 256: emit context_last + CLS_out for their n (head 7)
  if ((bid & 255) == 0) {
    {
      int kc = t >> 4, vc = t & 15;             // all 256 threads
      out[OUT_CTX + n * 256 + t] = ctxn[(112 + kc) * 16 + vc];
    }
    if (t < 64) {
      int vc = t >> 2, j = t & 3;
      float den = 0.f, num = 0.f;
      #pragma unroll
      for (int kc = 0; kc < 16; ++kc) {
        float e_ = __expf(CLS[(n * 128 + 112 + kc) * 4 + j]);
        den += e_;
        num += e_ * ctxn[(112 + kc) * 16 + vc];
      }
      out[OUT_CLS + n * 64 + t] = num / den;
    }
  }

  // M-build: mA[mt][ks] = A-frag of M[o][cc] = sum_v Wr[o][h*16+v]*ctx[h][cc&15][v]
  bf16x8 mA[2][4];
  for (int ks = 0; ks < 4; ++ks) {
    int h = 2 * ks + (quad >> 1);
    float4 wrv[2][4];
    #pragma unroll
    for (int mt = 0; mt < 2; ++mt) {
      const float* wp = Wr + ((w * 2 + mt) * 16 + lm) * 128 + h * 16;
      #pragma unroll
      for (int q4 = 0; q4 < 4; ++q4) wrv[mt][q4] = *(const float4*)(wp + q4 * 4);
    }
    short mr0[8], mr1[8];
    #pragma unroll
    for (int jj = 0; jj < 8; ++jj) {
      int k = (quad & 1) * 8 + jj;
      const float4* cp = (const float4*)&ctxn[(h * 16 + k) * 16];
      float4 c0 = cp[0], c1 = cp[1], c2 = cp[2], c3 = cp[3];
      float m0 = dot4(wrv[0][0], c0) + dot4(wrv[0][1], c1) + dot4(wrv[0][2], c2) + dot4(wrv[0][3], c3);
      float m1 = dot4(wrv[1][0], c0) + dot4(wrv[1][1], c1) + dot4(wrv[1][2], c2) + dot4(wrv[1][3], c3);
      mr0[jj] = (short)f2b(m0);
      mr1[jj] = (short)f2b(m1);
    }
    mA[0][ks] = *(bf16x8*)mr0;
    mA[1][ks] = *(bf16x8*)mr1;
  }

  // main loop; tile-0 barrier A orders all ctxn reads before qT reuses the space
  u16 (*qT)[136] = (u16 (*)[136])ubuf;
  floatx4 z4 = {0.f, 0.f, 0.f, 0.f};
  for (int tile = 0; tile < 4; ++tile) {
    int l0 = l0base + tile * 64;
    #pragma unroll
    for (int k = 0; k < 4; ++k)
      *(bf16x8*)&xT[sl][scq * 32 + k * 8] = pfb[k];
    if (tile < 3) {
      int l0n = l0base + (tile + 1) * 64;
      #pragma unroll
      for (int k = 0; k < 4; ++k)
        pfb[k] = *(const bf16x8*)(xbf + ((((size_t)n << 16) + l0n + sl) << 7) + scq * 32 + k * 8);
    }
    __syncthreads();                            // A: xT RAW + ubuf WAR

    floatx4 acc[2][4];
    #pragma unroll
    for (int mt = 0; mt < 2; ++mt)
      #pragma unroll
      for (int nt = 0; nt < 4; ++nt) acc[mt][nt] = z4;

    #pragma unroll
    for (int nt = 0; nt < 4; ++nt)
      #pragma unroll
      for (int ks = 0; ks < 4; ++ks) {
        bf16x8 b = *(const bf16x8*)&xT[nt * 16 + lm][ks * 32 + quad * 8];
        #pragma unroll
        for (int mt = 0; mt < 2; ++mt)
          acc[mt][nt] = __builtin_amdgcn_mfma_f32_16x16x32_bf16(wq[mt][ks], b, acc[mt][nt], 0, 0, 0);
      }

    // per-column softmax over the 16 channels of each head (wave-local)
    #pragma unroll
    for (int mt = 0; mt < 2; ++mt) {
      int h = w * 2 + mt;
      #pragma unroll
      for (int nt = 0; nt < 4; ++nt) {
        float e[4];
        float ssum = 0.f;
        #pragma unroll
        for (int j = 0; j < 4; ++j) {
          e[j] = __expf(acc[mt][nt][j] + bqv[mt][j]);
          ssum += e[j];
        }
        ssum += __shfl_xor(ssum, 16);
        ssum += __shfl_xor(ssum, 32);
        float inv = 1.f / ssum;
        short4v p;
        #pragma unroll
        for (int j = 0; j < 4; ++j) p[j] = (short)f2b(e[j] * inv);
        *(short4v*)&qT[nt * 16 + lm][h * 16 + quad * 4] = p;
      }
    }
    __syncthreads();                            // B: all heads' q channels ready

    floatx4 acc2[2][4];
    #pragma unroll
    for (int mt = 0; mt < 2; ++mt)
      #pragma unroll
      for (int nt = 0; nt < 4; ++nt) acc2[mt][nt] = z4;

    #pragma unroll
    for (int nt = 0; nt < 4; ++nt)
      #pragma unroll
      for (int ks = 0; ks < 4; ++ks) {
        bf16x8 b = *(const bf16x8*)&qT[nt * 16 + lm][ks * 32 + quad * 8];
        #pragma unroll
        for (int mt = 0; mt < 2; ++mt)
          acc2[mt][nt] = __builtin_amdgcn_mfma_f32_16x16x32_bf16(mA[mt][ks], b, acc2[mt][nt], 0, 0, 0);
      }

    #pragma unroll
    for (int mt = 0; mt < 2; ++mt)
      #pragma unroll
      for (int j = 0; j < 4; ++j) {
        int R = (w * 2 + mt) * 16 + quad * 4 + j;
        #pragma unroll
        for (int nt = 0; nt < 4; ++nt)
          out[(((size_t)(n * 128 + R)) << 16) + l0 + nt * 16 + lm] = acc2[mt][nt][j] + brv[mt][j];
      }
  }
}

extern "C" void kernel_launch(void* const* d_in, const int* in_sizes, int n_in,
                              void* d_out, int out_size, void* d_ws, size_t ws_size,
                              hipStream_t stream) {
  const float* x   = (const float*)d_in[0];
  const float* CLS = (const float*)d_in[1];
  const float* Wk  = (const float*)d_in[2];
  const float* bk  = (const float*)d_in[3];
  const float* Wq  = (const float*)d_in[4];
  const float* bq  = (const float*)d_in[5];
  const float* Wv  = (const float*)d_in[6];
  const float* bv  = (const float*)d_in[7];
  const float* Wr  = (const float*)d_in[8];
  const float* br  = (const float*)d_in[9];
  float* out = (float*)d_out;
  char* ws = (char*)d_ws;
  float* S2    = (float*)(ws + 0);        // 4 slots x 256 f32  = 4096 B
  float* Cnum2 = (float*)(ws + 4096);     // 4 slots x 4096 f32 = 65536 B
  u16* xbf     = (u16*)(ws + 69632);      // 2*65536*128 bf16 = 33.55 MB

  hipMemsetAsync(ws, 0, 69632, stream);   // accumulators only
  kA<<<512, 256, 0, stream>>>(x, Wk, bk, Wv, bv, S2, Cnum2, xbf);
  kB<<<512, 256, 0, stream>>>(xbf, CLS, Wq, bq, Wr, br, S2, Cnum2, out);
}

// Round 9
// 175.063 us; speedup vs baseline: 1.3610x; 1.0229x over previous
//
#include <hip/hip_runtime.h>

typedef unsigned short u16;
typedef short bf16x8 __attribute__((ext_vector_type(8)));
typedef short short4v __attribute__((ext_vector_type(4)));
typedef float floatx4 __attribute__((ext_vector_type(4)));

#define OUT_CTX 16777216           // 2*128*65536 attention elems
#define OUT_CLS (OUT_CTX + 512)

__device__ __forceinline__ u16 f2b(float f) {           // fp32 -> bf16 RNE
  unsigned int u = __float_as_uint(f);
  u += 0x7fffu + ((u >> 16) & 1u);
  return (u16)(u >> 16);
}
__device__ __forceinline__ float b2f(u16 b) { return __uint_as_float(((unsigned int)b) << 16); }

__device__ __forceinline__ bf16x8 pack8(const float* p) { // 8 consecutive f32 -> bf16x8
  float4 a = *(const float4*)p;
  float4 b = *(const float4*)(p + 4);
  bf16x8 r;
  r[0] = (short)f2b(a.x); r[1] = (short)f2b(a.y); r[2] = (short)f2b(a.z); r[3] = (short)f2b(a.w);
  r[4] = (short)f2b(b.x); r[5] = (short)f2b(b.y); r[6] = (short)f2b(b.z); r[7] = (short)f2b(b.w);
  return r;
}

__device__ __forceinline__ float dot4(float4 a, float4 b) {
  return a.x * b.x + a.y * b.y + a.z * b.z + a.w * b.w;
}

// ---- kA: K/V projection + exp + context/S accumulation (round-4/8 verified body).
//      512 blocks x 4 tiles of 64 cols. Swapped GEMM1 (A = x-tile, B = W rows):
//      ev epilogue writes are ds_write_b64, S partials lane-local.
//      NO xbf streaming (round-8 lesson: 33.6MB workspace costs ~28us of
//      harness re-poison per iteration — more than it saves in kernel time).
__global__ __launch_bounds__(256) void kA(
    const float* __restrict__ x, const float* __restrict__ Wk,
    const float* __restrict__ bk, const float* __restrict__ Wv,
    const float* __restrict__ bv, float* __restrict__ S2,
    float* __restrict__ Cnum2) {
  __shared__ __align__(16) u16 xT[64][136];     // [l][ch] bf16
  __shared__ __align__(16) u16 ev[256][72];     // rows 0..127 E, 128..255 V
  const int t = threadIdx.x;
  const int w = t >> 6, lane = t & 63;
  const int quad = lane >> 4, lm = lane & 15;
  const int bid = blockIdx.x;
  const int n = bid >> 8;                       // 512 blocks: 256 per batch
  const int l0base = (bid & 255) << 8;          // 256 cols per block
  const int slot = bid & 3;                     // 4 atomic slots
  const int sc = t >> 4, sl4 = t & 15;

  float4 pf[8];
  #pragma unroll
  for (int i = 0; i < 8; ++i)
    pf[i] = *(const float4*)(x + (((size_t)(n * 128 + sc * 8 + i)) << 16) + l0base + sl4 * 4);

  // W fragments as MFMA B-operand: nt 0,1 = Wk rows {w*32, w*32+16}+lm; nt 2,3 = Wv
  bf16x8 wf[4][4];
  #pragma unroll
  for (int nt = 0; nt < 4; ++nt) {
    const float* W = (nt < 2) ? Wk : Wv;
    int row = w * 32 + (nt & 1) * 16 + lm;
    #pragma unroll
    for (int ks = 0; ks < 4; ++ks)
      wf[nt][ks] = pack8(W + row * 128 + ks * 32 + quad * 8);
  }
  float biasE[2] = { bk[w * 32 + lm], bk[w * 32 + 16 + lm] };
  float biasV[2] = { bv[w * 32 + lm], bv[w * 32 + 16 + lm] };

  floatx4 z4 = {0.f, 0.f, 0.f, 0.f};
  floatx4 cacc[2] = {z4, z4};                   // context acc (2 heads per wave)
  float sacc[2] = {0.f, 0.f};                   // S partials, lane-local

  for (int tile = 0; tile < 4; ++tile) {
    const float* pff = (const float*)pf;
    #pragma unroll
    for (int r = 0; r < 4; ++r) {
      bf16x8 vx;
      #pragma unroll
      for (int i = 0; i < 8; ++i) vx[i] = (short)f2b(pff[i * 4 + r]);
      *(bf16x8*)&xT[sl4 * 4 + r][sc * 8] = vx;  // ds_write_b128
    }
    if (tile < 3) {
      int l0n = l0base + (tile + 1) * 64;
      #pragma unroll
      for (int i = 0; i < 8; ++i)
        pf[i] = *(const float4*)(x + (((size_t)(n * 128 + sc * 8 + i)) << 16) + l0n + sl4 * 4);
    }
    __syncthreads();                            // A: xT ready

    floatx4 acc[4][4];
    #pragma unroll
    for (int mt = 0; mt < 4; ++mt)
      #pragma unroll
      for (int nt = 0; nt < 4; ++nt) acc[mt][nt] = z4;

    #pragma unroll
    for (int mt = 0; mt < 4; ++mt)
      #pragma unroll
      for (int ks = 0; ks < 4; ++ks) {
        bf16x8 xa = *(const bf16x8*)&xT[mt * 16 + lm][ks * 32 + quad * 8];
        #pragma unroll
        for (int nt = 0; nt < 4; ++nt)
          acc[mt][nt] = __builtin_amdgcn_mfma_f32_16x16x32_bf16(xa, wf[nt][ks], acc[mt][nt], 0, 0, 0);
      }
    __syncthreads();                            // B: xT consumed, next stores safe

    // epilogue: D[m=l][n=ch]; ch = w*32+nt*16+lm, l = mt*16+quad*4+j -> b64 writes
    #pragma unroll
    for (int nt = 0; nt < 2; ++nt)
      #pragma unroll
      for (int mt = 0; mt < 4; ++mt) {
        short4v p;
        #pragma unroll
        for (int j = 0; j < 4; ++j) {
          float v = __expf(acc[mt][nt][j] + biasE[nt]);
          u16 b = f2b(v);
          sacc[nt] += b2f(b);
          p[j] = (short)b;
        }
        *(short4v*)&ev[w * 32 + nt * 16 + lm][mt * 16 + quad * 4] = p;
      }
    #pragma unroll
    for (int nt = 0; nt < 2; ++nt)
      #pragma unroll
      for (int mt = 0; mt < 4; ++mt) {
        short4v p;
        #pragma unroll
        for (int j = 0; j < 4; ++j)
          p[j] = (short)f2b(acc[mt][nt + 2][j] + biasV[nt]);
        *(short4v*)&ev[128 + w * 32 + nt * 16 + lm][mt * 16 + quad * 4] = p;
      }

    // context MFMAs: read ONLY this wave's own ev rows (same-wave DS order)
    #pragma unroll
    for (int hh = 0; hh < 2; ++hh) {
      int h = w * 2 + hh;
      #pragma unroll
      for (int ks = 0; ks < 2; ++ks) {
        bf16x8 aE = *(const bf16x8*)&ev[h * 16 + lm][ks * 32 + quad * 8];
        bf16x8 bV = *(const bf16x8*)&ev[128 + h * 16 + lm][ks * 32 + quad * 8];
        cacc[hh] = __builtin_amdgcn_mfma_f32_16x16x32_bf16(aE, bV, cacc[hh], 0, 0, 0);
      }
    }
  }

  float* Cn = Cnum2 + slot * 4096;
  #pragma unroll
  for (int hh = 0; hh < 2; ++hh) {
    int h = w * 2 + hh;
    #pragma unroll
    for (int j = 0; j < 4; ++j)
      atomicAdd(&Cn[((n * 8 + h) * 16 + quad * 4 + j) * 16 + lm], cacc[hh][j]);
  }
  #pragma unroll
  for (int nt = 0; nt < 2; ++nt) {
    float s = sacc[nt];
    s += __shfl_xor(s, 16);
    s += __shfl_xor(s, 32);
    if (quad == 0)
      atomicAdd(&S2[slot * 256 + n * 128 + w * 32 + nt * 16 + lm], s);
  }
}

// ---- kB: out = M * softmax_q(Wq x + bq) + br. 512 blocks x 4 tiles of 64 cols.
//      R8 structure (M-fold prologue, ctxn/qT LDS union, parallel per-block
//      ctx finalize with plain loads) with f32 x staging (R4-verified code).
__global__ __launch_bounds__(256) void kB(
    const float* __restrict__ x, const float* __restrict__ CLS,
    const float* __restrict__ Wq, const float* __restrict__ bq,
    const float* __restrict__ Wr, const float* __restrict__ br,
    const float* __restrict__ S2, const float* __restrict__ Cnum2,
    float* __restrict__ out) {
  __shared__ __align__(16) u16 xT[64][136];     // [l][ch] bf16, 17408 B
  __shared__ __align__(16) u16 ubuf[64 * 136];  // prologue: f32 ctxn[2048]; main: qT
  const int t = threadIdx.x;
  const int w = t >> 6, lane = t & 63;
  const int quad = lane >> 4, lm = lane & 15;
  const int bid = blockIdx.x;
  const int n = bid >> 8;                       // 512 blocks: 256 per batch
  const int l0base = (bid & 255) << 8;          // 256 cols per block
  const int sc = t >> 4, sl4 = t & 15;

  float4 pf[8];
  #pragma unroll
  for (int i = 0; i < 8; ++i)
    pf[i] = *(const float4*)(x + (((size_t)(n * 128 + sc * 8 + i)) << 16) + l0base + sl4 * 4);

  bf16x8 wq[2][4];
  #pragma unroll
  for (int mt = 0; mt < 2; ++mt) {
    int row = (w * 2 + mt) * 16 + lm;
    #pragma unroll
    for (int ks = 0; ks < 4; ++ks)
      wq[mt][ks] = pack8(Wq + row * 128 + ks * 32 + quad * 8);
  }
  float bqv[2][4], brv[2][4];
  #pragma unroll
  for (int mt = 0; mt < 2; ++mt)
    #pragma unroll
    for (int j = 0; j < 4; ++j) {
      bqv[mt][j] = bq[(w * 2 + mt) * 16 + quad * 4 + j];
      brv[mt][j] = br[(w * 2 + mt) * 16 + quad * 4 + j];
    }

  // stage ctx = (sum Cnum slots + CLS num) / (sum S slots + CLS den) into LDS
  float* ctxn = (float*)ubuf;                   // [h*16+k][v] f32, this block's n
  {
    int hk = t >> 1, v0 = (t & 1) * 8;          // hk 0..127, v0 0 or 8
    int hbase = hk & 0x70;                      // h*16
    float ek[4];
    float den = 0.f;
    #pragma unroll
    for (int j = 0; j < 4; ++j) {
      ek[j] = __expf(CLS[(n * 128 + hk) * 4 + j]);
      den += ek[j];
    }
    #pragma unroll
    for (int s = 0; s < 4; ++s) den += S2[s * 256 + n * 128 + hk];
    float inv = 1.f / den;
    float vv[8];
    #pragma unroll
    for (int i = 0; i < 8; ++i) {
      int v = v0 + i;
      float num = 0.f;
      #pragma unroll
      for (int s = 0; s < 4; ++s) num += Cnum2[s * 4096 + (n * 128 + hk) * 16 + v];
      #pragma unroll
      for (int j = 0; j < 4; ++j) num += ek[j] * CLS[(n * 128 + hbase + v) * 4 + j];
      vv[i] = num * inv;
    }
    float4 a = {vv[0], vv[1], vv[2], vv[3]}, b = {vv[4], vv[5], vv[6], vv[7]};
    *(float4*)&ctxn[hk * 16 + v0] = a;
    *(float4*)&ctxn[hk * 16 + v0 + 4] = b;
  }
  __syncthreads();                              // ctxn ready

  // blocks 0 / 256: emit context_last + CLS_out for their n (head 7)
  if ((bid & 255) == 0) {
    {
      int kc = t >> 4, vc = t & 15;             // all 256 threads
      out[OUT_CTX + n * 256 + t] = ctxn[(112 + kc) * 16 + vc];
    }
    if (t < 64) {
      int vc = t >> 2, j = t & 3;
      float den = 0.f, num = 0.f;
      #pragma unroll
      for (int kc = 0; kc < 16; ++kc) {
        float e_ = __expf(CLS[(n * 128 + 112 + kc) * 4 + j]);
        den += e_;
        num += e_ * ctxn[(112 + kc) * 16 + vc];
      }
      out[OUT_CLS + n * 64 + t] = num / den;
    }
  }

  // M-build: mA[mt][ks] = A-frag of M[o][cc] = sum_v Wr[o][h*16+v]*ctx[h][cc&15][v]
  bf16x8 mA[2][4];
  for (int ks = 0; ks < 4; ++ks) {
    int h = 2 * ks + (quad >> 1);
    float4 wrv[2][4];
    #pragma unroll
    for (int mt = 0; mt < 2; ++mt) {
      const float* wp = Wr + ((w * 2 + mt) * 16 + lm) * 128 + h * 16;
      #pragma unroll
      for (int q4 = 0; q4 < 4; ++q4) wrv[mt][q4] = *(const float4*)(wp + q4 * 4);
    }
    short mr0[8], mr1[8];
    #pragma unroll
    for (int jj = 0; jj < 8; ++jj) {
      int k = (quad & 1) * 8 + jj;
      const float4* cp = (const float4*)&ctxn[(h * 16 + k) * 16];
      float4 c0 = cp[0], c1 = cp[1], c2 = cp[2], c3 = cp[3];
      float m0 = dot4(wrv[0][0], c0) + dot4(wrv[0][1], c1) + dot4(wrv[0][2], c2) + dot4(wrv[0][3], c3);
      float m1 = dot4(wrv[1][0], c0) + dot4(wrv[1][1], c1) + dot4(wrv[1][2], c2) + dot4(wrv[1][3], c3);
      mr0[jj] = (short)f2b(m0);
      mr1[jj] = (short)f2b(m1);
    }
    mA[0][ks] = *(bf16x8*)mr0;
    mA[1][ks] = *(bf16x8*)mr1;
  }

  // main loop; tile-0 barrier A orders all ctxn reads before qT reuses the space
  u16 (*qT)[136] = (u16 (*)[136])ubuf;
  floatx4 z4 = {0.f, 0.f, 0.f, 0.f};
  for (int tile = 0; tile < 4; ++tile) {
    int l0 = l0base + tile * 64;
    const float* pff = (const float*)pf;
    #pragma unroll
    for (int r = 0; r < 4; ++r) {
      bf16x8 vx;
      #pragma unroll
      for (int i = 0; i < 8; ++i) vx[i] = (short)f2b(pff[i * 4 + r]);
      *(bf16x8*)&xT[sl4 * 4 + r][sc * 8] = vx;
    }
    if (tile < 3) {
      int l0n = l0base + (tile + 1) * 64;
      #pragma unroll
      for (int i = 0; i < 8; ++i)
        pf[i] = *(const float4*)(x + (((size_t)(n * 128 + sc * 8 + i)) << 16) + l0n + sl4 * 4);
    }
    __syncthreads();                            // A: xT RAW + ubuf WAR

    floatx4 acc[2][4];
    #pragma unroll
    for (int mt = 0; mt < 2; ++mt)
      #pragma unroll
      for (int nt = 0; nt < 4; ++nt) acc[mt][nt] = z4;

    #pragma unroll
    for (int nt = 0; nt < 4; ++nt)
      #pragma unroll
      for (int ks = 0; ks < 4; ++ks) {
        bf16x8 b = *(const bf16x8*)&xT[nt * 16 + lm][ks * 32 + quad * 8];
        #pragma unroll
        for (int mt = 0; mt < 2; ++mt)
          acc[mt][nt] = __builtin_amdgcn_mfma_f32_16x16x32_bf16(wq[mt][ks], b, acc[mt][nt], 0, 0, 0);
      }

    // per-column softmax over the 16 channels of each head (wave-local)
    #pragma unroll
    for (int mt = 0; mt < 2; ++mt) {
      int h = w * 2 + mt;
      #pragma unroll
      for (int nt = 0; nt < 4; ++nt) {
        float e[4];
        float ssum = 0.f;
        #pragma unroll
        for (int j = 0; j < 4; ++j) {
          e[j] = __expf(acc[mt][nt][j] + bqv[mt][j]);
          ssum += e[j];
        }
        ssum += __shfl_xor(ssum, 16);
        ssum += __shfl_xor(ssum, 32);
        float inv = 1.f / ssum;
        short4v p;
        #pragma unroll
        for (int j = 0; j < 4; ++j) p[j] = (short)f2b(e[j] * inv);
        *(short4v*)&qT[nt * 16 + lm][h * 16 + quad * 4] = p;
      }
    }
    __syncthreads();                            // B: all heads' q channels ready

    floatx4 acc2[2][4];
    #pragma unroll
    for (int mt = 0; mt < 2; ++mt)
      #pragma unroll
      for (int nt = 0; nt < 4; ++nt) acc2[mt][nt] = z4;

    #pragma unroll
    for (int nt = 0; nt < 4; ++nt)
      #pragma unroll
      for (int ks = 0; ks < 4; ++ks) {
        bf16x8 b = *(const bf16x8*)&qT[nt * 16 + lm][ks * 32 + quad * 8];
        #pragma unroll
        for (int mt = 0; mt < 2; ++mt)
          acc2[mt][nt] = __builtin_amdgcn_mfma_f32_16x16x32_bf16(mA[mt][ks], b, acc2[mt][nt], 0, 0, 0);
      }

    #pragma unroll
    for (int mt = 0; mt < 2; ++mt)
      #pragma unroll
      for (int j = 0; j < 4; ++j) {
        int R = (w * 2 + mt) * 16 + quad * 4 + j;
        #pragma unroll
        for (int nt = 0; nt < 4; ++nt)
          out[(((size_t)(n * 128 + R)) << 16) + l0 + nt * 16 + lm] = acc2[mt][nt][j] + brv[mt][j];
      }
  }
}

extern "C" void kernel_launch(void* const* d_in, const int* in_sizes, int n_in,
                              void* d_out, int out_size, void* d_ws, size_t ws_size,
                              hipStream_t stream) {
  const float* x   = (const float*)d_in[0];
  const float* CLS = (const float*)d_in[1];
  const float* Wk  = (const float*)d_in[2];
  const float* bk  = (const float*)d_in[3];
  const float* Wq  = (const float*)d_in[4];
  const float* bq  = (const float*)d_in[5];
  const float* Wv  = (const float*)d_in[6];
  const float* bv  = (const float*)d_in[7];
  const float* Wr  = (const float*)d_in[8];
  const float* br  = (const float*)d_in[9];
  float* out = (float*)d_out;
  char* ws = (char*)d_ws;
  float* S2    = (float*)(ws + 0);        // 4 slots x 256 f32  = 4096 B
  float* Cnum2 = (float*)(ws + 4096);     // 4 slots x 4096 f32 = 65536 B

  hipMemsetAsync(ws, 0, 69632, stream);   // accumulators only (small ws!)
  kA<<<512, 256, 0, stream>>>(x, Wk, bk, Wv, bv, S2, Cnum2);
  kB<<<512, 256, 0, stream>>>(x, CLS, Wq, bq, Wr, br, S2, Cnum2, out);
}